// Round 7
// baseline (585.847 us; speedup 1.0000x reference)
//
#include <hip/hip_runtime.h>

// Problem constants
#define SRC    16384     // 128*128 source pixels
#define DCH    64        // channels
#define NCLS   19        // classes
#define NPAIR  (NCLS*DCH)// 1216 (c,d) pairs

// GUARANTEED bare v_exp_f32 via inline asm (proven in the 87.9us session).
// CDNA VALU->VALU results are hardware-interlocked; no s_nop required.
__device__ __forceinline__ float exp2_raw(float x)
{
    float r;
    asm("v_exp_f32 %0, %1" : "=v"(r) : "v"(x));
    return r;
}

// ---------------------------------------------------------------------------
// K1: per-source-pixel class counts (proven). Also zeroes psum.
// ---------------------------------------------------------------------------
__global__ __launch_bounds__(256) void hl_count_kernel(
    const int* __restrict__ label, unsigned char* __restrict__ cnt,
    float* __restrict__ psum)
{
    if (blockIdx.x == 0 && threadIdx.x == 0) psum[0] = 0.f;
    int s  = blockIdx.x * 256 + threadIdx.x;   // 64 blocks x 256 = 16384
    int sy = s >> 7, sx = s & 127;
    const int4* lab4 = (const int4*)label;
    int l[16];
#pragma unroll
    for (int r = 0; r < 4; r++) {
        int4 v = lab4[(4 * sy + r) * 128 + sx];
        l[4 * r + 0] = v.x; l[4 * r + 1] = v.y;
        l[4 * r + 2] = v.z; l[4 * r + 3] = v.w;
    }
#pragma unroll
    for (int c = 0; c < NCLS; c++) {
        int cc = 0;
#pragma unroll
        for (int j = 0; j < 16; j++) cc += (l[j] == c) ? 1 : 0;
        cnt[c * SRC + s] = (unsigned char)cc;
    }
}

// ---------------------------------------------------------------------------
// K2: fused moments + KDE. One 256-thread block per (c,d), 64 px/thread.
// Pass 1: proven f64-reduced moments.
// Pass 2 (trans-bound fix): 7 exps/element -> 3 exps/element.
//   arg_k = C1*(u-k)^2. Center on k0 = rint(clamp(u,-3,3)), v = u-k0:
//     term(o) = e^{-12.5 (v-o)^2}, o = k-k0, only |o|<=2 matter
//     (|o|>=3 terms <= e^{-78}: invisible in an f32 sum of O(1e3)).
//   t0 = cf*exp2(C1 v^2); r = exp2(C2 v); ri = exp2(-C2 v)     [3 trans]
//   t1 = t0*(r*K1c); t2 = t1*(r*K2c); tm1 = t0*(ri*K1c); tm2 = tm1*(ri*K2c)
//   (chain values are the true bin values, all intermediates finite with
//    v clamped to +-3.4: 2^(C2*3.4) = 7.9e36 < f32 max; clamping only
//    affects |u|>6.4 where every true bin underflows to 0 anyway).
//   Runtime destination bin k0+o -> per-thread-private LDS histogram
//   columns hist[slot][t] (slot = k0+3 for o=-2, +1 slot per o), updated
//   with ds_add_f32 (bank = t%32: conflict-free, no cross-thread races).
//   Trans/el: 7->3 (224->96 cyc), VALU ~23 (46 cyc), DS 5 (30 cyc).
// launch_bounds(256,4): proven no-spill budget.
// ---------------------------------------------------------------------------
__global__ __launch_bounds__(256, 4) void hl_fused_kernel(
    const float* __restrict__ feature, const unsigned char* __restrict__ cnt,
    int* __restrict__ ncls, float* __restrict__ psum)
{
    int w = blockIdx.x;             // pair 0..1215
    int c = w >> 6, d = w & 63;
    int t = threadIdx.x;
    int wid = t >> 6;

    const float4*       fp4 = (const float4*)(feature + d * SRC);
    const unsigned int* cpu = (const unsigned int*)(cnt + c * SRC);

    // ---- Pass 1: moments (proven) -----------------------------------------
    float f1 = 0.f, f2 = 0.f;
    int   nc = 0;
#pragma unroll 4
    for (int i = 0; i < 16; i++) {
        int g = i * 256 + t;        // 4096 float4-groups (= 4096 uint groups)
        float4       x  = fp4[g];
        unsigned int cv = cpu[g];
        float xs[4] = {x.x, x.y, x.z, x.w};
        float cf[4] = {(float)(cv & 255u), (float)((cv >> 8) & 255u),
                       (float)((cv >> 16) & 255u), (float)(cv >> 24)};
#pragma unroll
        for (int e = 0; e < 4; e++) {
            float wx = cf[e] * xs[e];
            f1 += wx;
            f2 = fmaf(wx, xs[e], f2);
        }
        nc += (cv & 255u) + ((cv >> 8) & 255u) + ((cv >> 16) & 255u) + (cv >> 24);
    }
    double s1 = (double)f1, s2 = (double)f2;
#pragma unroll
    for (int o = 32; o > 0; o >>= 1) {
        s1 += __shfl_down(s1, o);
        s2 += __shfl_down(s2, o);
        nc += __shfl_down(nc, o);
    }
    __shared__ double ps1[4], ps2[4];
    __shared__ int    pn[4];
    __shared__ float  sh_mu, sh_istd;
    __shared__ int    sh_act;
    if ((t & 63) == 0) { ps1[wid] = s1; ps2[wid] = s2; pn[wid] = nc; }
    __syncthreads();
    if (t == 0) {
        double a = ps1[0] + ps1[1] + ps1[2] + ps1[3];
        double b = ps2[0] + ps2[1] + ps2[2] + ps2[3];
        int    n = pn[0] + pn[1] + pn[2] + pn[3];
        double nsafe = (n > 0) ? (double)n : 1.0;
        double mu  = a / nsafe;
        double var = (b - 2.0 * mu * a + mu * mu * (double)n) / nsafe + 1e-10;
        sh_mu   = (float)mu;
        sh_istd = (float)(1.0 / sqrt(var));
        sh_act  = (n >= 1000);
        if (d == 0) ncls[c] = n;    // plain store; consumed only by K3
    }
    __syncthreads();
    if (!sh_act) return;            // inactive class: contributes 0
    float istd = sh_istd;
    float nm   = -sh_mu * istd;     // u = fma(x, istd, nm)

    // ---- Pass 2: KDE, 3-trans centered form (data is L1/L2-hot) -----------
    const float C1  = -18.033688011112042f;  // -12.5 * log2(e)
    const float C2  =  36.067376022224084f;  // +25   * log2(e)
    const float K1c =  3.72665317e-06f;      // e^{-12.5}
    const float K2c =  5.17555501e-17f;      // e^{-37.5}

    // per-thread private LDS histogram columns: hist[slot][t], slot 0..10
    __shared__ float hist[11][256];
#pragma unroll
    for (int s3 = 0; s3 < 11; s3++) hist[s3][t] = 0.f;

#pragma unroll 2
    for (int i = 0; i < 16; i++) {
        int g = i * 256 + t;
        float4       x  = fp4[g];
        unsigned int cv = cpu[g];
        float xs[4] = {x.x, x.y, x.z, x.w};
        float cf[4] = {(float)(cv & 255u), (float)((cv >> 8) & 255u),
                       (float)((cv >> 16) & 255u), (float)(cv >> 24)};
#pragma unroll
        for (int e = 0; e < 4; e++) {
            float u   = fmaf(xs[e], istd, nm);
            float uc  = fminf(3.f, fmaxf(-3.f, u));
            float k0f = rintf(uc);                       // v_rndne, exact int
            float v   = u - k0f;
            v = fminf(3.4f, fmaxf(-3.4f, v));            // overflow guard only
            float E   = exp2_raw((C1 * v) * v);          // e^{-12.5 v^2}
            float r   = exp2_raw(C2 * v);                // e^{+25 v}
            float ri  = exp2_raw(-C2 * v);               // e^{-25 v}
            float t0  = cf[e] * E;
            float t1  = t0  * (r  * K1c);                // e^{-12.5(v-1)^2}
            float t2  = t1  * (r  * K2c);                // e^{-12.5(v-2)^2}
            float tm1 = t0  * (ri * K1c);                // e^{-12.5(v+1)^2}
            float tm2 = tm1 * (ri * K2c);                // e^{-12.5(v+2)^2}
            int   k0i = (int)k0f;                        // -3..3
            float* col = &hist[k0i + 3][t];              // slot for o = -2
            __hip_atomic_fetch_add(col,        tm2, __ATOMIC_RELAXED, __HIP_MEMORY_SCOPE_WORKGROUP);
            __hip_atomic_fetch_add(col + 256,  tm1, __ATOMIC_RELAXED, __HIP_MEMORY_SCOPE_WORKGROUP);
            __hip_atomic_fetch_add(col + 512,  t0,  __ATOMIC_RELAXED, __HIP_MEMORY_SCOPE_WORKGROUP);
            __hip_atomic_fetch_add(col + 768,  t1,  __ATOMIC_RELAXED, __HIP_MEMORY_SCOPE_WORKGROUP);
            __hip_atomic_fetch_add(col + 1024, t2,  __ATOMIC_RELAXED, __HIP_MEMORY_SCOPE_WORKGROUP);
        }
    }
    __syncthreads();   // drain ds_adds before reading own columns

    // bin j (k = j-3) lives in slot k+5 = j+2; slots 0,1,9,10 are discards
    float acc[7];
#pragma unroll
    for (int j = 0; j < 7; j++) acc[j] = hist[j + 2][t];

    __shared__ float part[4][7];
#pragma unroll
    for (int j = 0; j < 7; j++) {
        float v = acc[j];
#pragma unroll
        for (int o = 32; o > 0; o >>= 1) v += __shfl_down(v, o);
        if ((t & 63) == 0) part[wid][j] = v;
    }
    __syncthreads();

    if (t == 0) {
        // target: exp(-0.5 k^2)/Z (1/sqrt(2 pi var) cancels in normalization)
        double e[7], z = 0.0;
#pragma unroll
        for (int k = -3; k <= 3; k++) { e[k + 3] = exp(-0.5 * (double)(k * k)); z += e[k + 3]; }

        float hist7[7], S = 0.f;
#pragma unroll
        for (int j = 0; j < 7; j++) {
            hist7[j] = part[0][j] + part[1][j] + part[2][j] + part[3][j];
            S += hist7[j];
        }
        float Ss = fmaxf(S, 1e-30f);
        float ps = 0.f;
#pragma unroll
        for (int j = 0; j < 7; j++) {
            float dd = fabsf(hist7[j] / Ss - (float)(e[j] / z));
            ps += (dd < 1.f) ? 0.5f * dd * dd : (dd - 0.5f);
        }
        atomicAdd(psum, ps);        // raw partial; scaled once in K3
    }
}

// ---------------------------------------------------------------------------
// K3: finalize. A = #active classes; out = psum / (448 * A). Writes out
// absolutely (harness-poisoned d_out needs no pre-zero).
// ---------------------------------------------------------------------------
__global__ __launch_bounds__(64) void hl_final_kernel(
    const float* __restrict__ psum, const int* __restrict__ ncls,
    float* __restrict__ out)
{
    if (threadIdx.x == 0) {
        int A = 0;
#pragma unroll
        for (int i = 0; i < NCLS; i++) A += (ncls[i] >= 1000) ? 1 : 0;
        out[0] = (A > 0) ? psum[0] / (448.0f * (float)A) : 0.0f;
    }
}

// ---------------------------------------------------------------------------
extern "C" void kernel_launch(void* const* d_in, const int* in_sizes, int n_in,
                              void* d_out, int out_size, void* d_ws, size_t ws_size,
                              hipStream_t stream)
{
    const float* feature = (const float*)d_in[0];   // [1,64,128,128] fp32
    const int*   label   = (const int*)d_in[1];     // [1,1,512,512]  int32
    float*       out     = (float*)d_out;           // scalar fp32

    char* ws = (char*)d_ws;
    unsigned char* cnt  = (unsigned char*)(ws);      // 311296 B
    int*           ncls = (int*)(ws + 311296);       // 76 B
    float*         psum = (float*)(ws + 311424);     // 4 B

    hl_count_kernel<<<SRC / 256, 256, 0, stream>>>(label, cnt, psum);
    hl_fused_kernel<<<NPAIR, 256, 0, stream>>>(feature, cnt, ncls, psum);
    hl_final_kernel<<<1, 64, 0, stream>>>(psum, ncls, out);
}

// Round 10
// 95.262 us; speedup vs baseline: 6.1499x; 6.1499x over previous
//
#include <hip/hip_runtime.h>

// Problem constants
#define SRC    16384     // 128*128 source pixels
#define DCH    64        // channels
#define NCLS   19        // classes
#define NPAIR  (NCLS*DCH)// 1216 (c,d) pairs

// GUARANTEED bare v_exp_f32 via inline asm (proven in the 87.9us session).
// CDNA VALU->VALU results are hardware-interlocked; no s_nop required.
__device__ __forceinline__ float exp2_raw(float x)
{
    float r;
    asm("v_exp_f32 %0, %1" : "=v"(r) : "v"(x));
    return r;
}

// ---------------------------------------------------------------------------
// K1: per-source-pixel class counts (proven). Also zeroes psum.
// ---------------------------------------------------------------------------
__global__ __launch_bounds__(256) void hl_count_kernel(
    const int* __restrict__ label, unsigned char* __restrict__ cnt,
    float* __restrict__ psum)
{
    if (blockIdx.x == 0 && threadIdx.x == 0) psum[0] = 0.f;
    int s  = blockIdx.x * 256 + threadIdx.x;   // 64 blocks x 256 = 16384
    int sy = s >> 7, sx = s & 127;
    const int4* lab4 = (const int4*)label;
    int l[16];
#pragma unroll
    for (int r = 0; r < 4; r++) {
        int4 v = lab4[(4 * sy + r) * 128 + sx];
        l[4 * r + 0] = v.x; l[4 * r + 1] = v.y;
        l[4 * r + 2] = v.z; l[4 * r + 3] = v.w;
    }
#pragma unroll
    for (int c = 0; c < NCLS; c++) {
        int cc = 0;
#pragma unroll
        for (int j = 0; j < 16; j++) cc += (l[j] == c) ? 1 : 0;
        cnt[c * SRC + s] = (unsigned char)cc;
    }
}

// ---------------------------------------------------------------------------
// K2: fused moments + KDE. One 256-thread block per (c,d), 64 px/thread.
// Pass 1: proven f64-reduced moments.
// Pass 2: 3-exp centered KDE (R7 post-mortem fix: NO LDS ATOMICS).
//   R7 used __hip_atomic_fetch_add on LDS floats -> compiler emitted a
//   CAS retry loop (no ds_add_f32 without unsafe-fp-atomics), 533us,
//   VALUBusy 3.4%. But the histogram columns hist[*][t] are THREAD-PRIVATE:
//   plain read-modify-write is race-free (same-wave LDS ops are in-order,
//   no cross-thread access until each thread reads back its own column).
//   Math (unchanged from R7, was never falsified):
//     arg_k = C1*(u-k)^2. Center k0 = rint(clamp(u,-3,3)), v = u-k0:
//     only offsets |o|<=2 matter (|o|>=3 terms <= e^{-78}).
//     E = exp2(C1 v^2); r = exp2(C2 v); ri = exp2(-C2 v)     [3 trans]
//     t0 = cf*E; t1 = t0*(r*K1c); t2 = t1*(r*K2c);
//     tm1 = t0*(ri*K1c); tm2 = tm1*(ri*K2c)
//     (all intermediates finite with v clamped to +-3.4; the clamp binds
//      only where every real bin underflows to 0 anyway).
//   Destination slot = k0+3+(o+2) in [0,10]; real bin j lives at slot j+2.
//   Bank = (slot*256+t)%32 = t%32: 2-way alias across 64 lanes = free.
//   Per wave-el: trans 3x32=96cy, VALU ~22x2=44cy, DS 10x6=60cy -> ~120cy
//   vs 300cy measured for the 7-exp form.
// launch_bounds(256,4): proven no-spill budget.
// ---------------------------------------------------------------------------
__global__ __launch_bounds__(256, 4) void hl_fused_kernel(
    const float* __restrict__ feature, const unsigned char* __restrict__ cnt,
    int* __restrict__ ncls, float* __restrict__ psum)
{
    int w = blockIdx.x;             // pair 0..1215
    int c = w >> 6, d = w & 63;
    int t = threadIdx.x;
    int wid = t >> 6;

    const float4*       fp4 = (const float4*)(feature + d * SRC);
    const unsigned int* cpu = (const unsigned int*)(cnt + c * SRC);

    // ---- Pass 1: moments (proven) -----------------------------------------
    float f1 = 0.f, f2 = 0.f;
    int   nc = 0;
#pragma unroll 4
    for (int i = 0; i < 16; i++) {
        int g = i * 256 + t;        // 4096 float4-groups (= 4096 uint groups)
        float4       x  = fp4[g];
        unsigned int cv = cpu[g];
        float xs[4] = {x.x, x.y, x.z, x.w};
        float cf[4] = {(float)(cv & 255u), (float)((cv >> 8) & 255u),
                       (float)((cv >> 16) & 255u), (float)(cv >> 24)};
#pragma unroll
        for (int e = 0; e < 4; e++) {
            float wx = cf[e] * xs[e];
            f1 += wx;
            f2 = fmaf(wx, xs[e], f2);
        }
        nc += (cv & 255u) + ((cv >> 8) & 255u) + ((cv >> 16) & 255u) + (cv >> 24);
    }
    double s1 = (double)f1, s2 = (double)f2;
#pragma unroll
    for (int o = 32; o > 0; o >>= 1) {
        s1 += __shfl_down(s1, o);
        s2 += __shfl_down(s2, o);
        nc += __shfl_down(nc, o);
    }
    __shared__ double ps1[4], ps2[4];
    __shared__ int    pn[4];
    __shared__ float  sh_mu, sh_istd;
    __shared__ int    sh_act;
    if ((t & 63) == 0) { ps1[wid] = s1; ps2[wid] = s2; pn[wid] = nc; }
    __syncthreads();
    if (t == 0) {
        double a = ps1[0] + ps1[1] + ps1[2] + ps1[3];
        double b = ps2[0] + ps2[1] + ps2[2] + ps2[3];
        int    n = pn[0] + pn[1] + pn[2] + pn[3];
        double nsafe = (n > 0) ? (double)n : 1.0;
        double mu  = a / nsafe;
        double var = (b - 2.0 * mu * a + mu * mu * (double)n) / nsafe + 1e-10;
        sh_mu   = (float)mu;
        sh_istd = (float)(1.0 / sqrt(var));
        sh_act  = (n >= 1000);
        if (d == 0) ncls[c] = n;    // plain store; consumed only by K3
    }
    __syncthreads();
    if (!sh_act) return;            // inactive class: contributes 0
    float istd = sh_istd;
    float nm   = -sh_mu * istd;     // u = fma(x, istd, nm)

    // ---- Pass 2: KDE, 3-trans centered form (data is L1/L2-hot) -----------
    const float C1  = -18.033688011112042f;  // -12.5 * log2(e)
    const float C2  =  36.067376022224084f;  // +25   * log2(e)
    const float K1c =  3.72665317e-06f;      // e^{-12.5}
    const float K2c =  5.17555501e-17f;      // e^{-37.5}

    // per-thread private LDS histogram columns: hist[slot][t], slot 0..10
    __shared__ float hist[11][256];
#pragma unroll
    for (int s3 = 0; s3 < 11; s3++) hist[s3][t] = 0.f;

#pragma unroll 2
    for (int i = 0; i < 16; i++) {
        int g = i * 256 + t;
        float4       x  = fp4[g];
        unsigned int cv = cpu[g];
        float xs[4] = {x.x, x.y, x.z, x.w};
        float cf[4] = {(float)(cv & 255u), (float)((cv >> 8) & 255u),
                       (float)((cv >> 16) & 255u), (float)(cv >> 24)};
#pragma unroll
        for (int e = 0; e < 4; e++) {
            float u   = fmaf(xs[e], istd, nm);
            float uc  = fminf(3.f, fmaxf(-3.f, u));
            float k0f = rintf(uc);                       // v_rndne, exact int
            float v   = u - k0f;
            v = fminf(3.4f, fmaxf(-3.4f, v));            // overflow guard only
            float c2v = C2 * v;
            float E   = exp2_raw((C1 * v) * v);          // e^{-12.5 v^2}
            float r   = exp2_raw(c2v);                   // e^{+25 v}
            float ri  = exp2_raw(-c2v);                  // e^{-25 v}
            float t0  = cf[e] * E;
            float t1  = t0  * (r  * K1c);                // e^{-12.5(v-1)^2}
            float t2  = t1  * (r  * K2c);                // e^{-12.5(v-2)^2}
            float tm1 = t0  * (ri * K1c);                // e^{-12.5(v+1)^2}
            float tm2 = tm1 * (ri * K2c);                // e^{-12.5(v+2)^2}
            int   k0i = (int)k0f;                        // -3..3
            // thread-private column: plain in-order LDS RMW, NO atomics
            float* col = &hist[k0i + 3][t];              // slot for o = -2
            col[0]        += tm2;
            col[256]      += tm1;
            col[2 * 256]  += t0;
            col[3 * 256]  += t1;
            col[4 * 256]  += t2;
        }
    }
    // No barrier needed: each thread reads only its own column, and
    // same-wave LDS ops complete in order.

    // bin j (k = j-3) lives in slot k+5 = j+2; slots 0,1,9,10 are discards
    float acc[7];
#pragma unroll
    for (int j = 0; j < 7; j++) acc[j] = hist[j + 2][t];

    __shared__ float part[4][7];
#pragma unroll
    for (int j = 0; j < 7; j++) {
        float v = acc[j];
#pragma unroll
        for (int o = 32; o > 0; o >>= 1) v += __shfl_down(v, o);
        if ((t & 63) == 0) part[wid][j] = v;
    }
    __syncthreads();

    if (t == 0) {
        // target: exp(-0.5 k^2)/Z (1/sqrt(2 pi var) cancels in normalization)
        double e[7], z = 0.0;
#pragma unroll
        for (int k = -3; k <= 3; k++) { e[k + 3] = exp(-0.5 * (double)(k * k)); z += e[k + 3]; }

        float hist7[7], S = 0.f;
#pragma unroll
        for (int j = 0; j < 7; j++) {
            hist7[j] = part[0][j] + part[1][j] + part[2][j] + part[3][j];
            S += hist7[j];
        }
        float Ss = fmaxf(S, 1e-30f);
        float ps = 0.f;
#pragma unroll
        for (int j = 0; j < 7; j++) {
            float dd = fabsf(hist7[j] / Ss - (float)(e[j] / z));
            ps += (dd < 1.f) ? 0.5f * dd * dd : (dd - 0.5f);
        }
        atomicAdd(psum, ps);        // raw partial; scaled once in K3
    }
}

// ---------------------------------------------------------------------------
// K3: finalize. A = #active classes; out = psum / (448 * A). Writes out
// absolutely (harness-poisoned d_out needs no pre-zero).
// ---------------------------------------------------------------------------
__global__ __launch_bounds__(64) void hl_final_kernel(
    const float* __restrict__ psum, const int* __restrict__ ncls,
    float* __restrict__ out)
{
    if (threadIdx.x == 0) {
        int A = 0;
#pragma unroll
        for (int i = 0; i < NCLS; i++) A += (ncls[i] >= 1000) ? 1 : 0;
        out[0] = (A > 0) ? psum[0] / (448.0f * (float)A) : 0.0f;
    }
}

// ---------------------------------------------------------------------------
extern "C" void kernel_launch(void* const* d_in, const int* in_sizes, int n_in,
                              void* d_out, int out_size, void* d_ws, size_t ws_size,
                              hipStream_t stream)
{
    const float* feature = (const float*)d_in[0];   // [1,64,128,128] fp32
    const int*   label   = (const int*)d_in[1];     // [1,1,512,512]  int32
    float*       out     = (float*)d_out;           // scalar fp32

    char* ws = (char*)d_ws;
    unsigned char* cnt  = (unsigned char*)(ws);      // 311296 B
    int*           ncls = (int*)(ws + 311296);       // 76 B
    float*         psum = (float*)(ws + 311424);     // 4 B

    hl_count_kernel<<<SRC / 256, 256, 0, stream>>>(label, cnt, psum);
    hl_fused_kernel<<<NPAIR, 256, 0, stream>>>(feature, cnt, ncls, psum);
    hl_final_kernel<<<1, 64, 0, stream>>>(psum, ncls, out);
}